// Round 9
// baseline (8068.780 us; speedup 1.0000x reference)
//
#include <hip/hip_runtime.h>

#define NB 32
#define NPTS 131072
#define KSAMP 2048
#define NPART 8
#define TPB 512
#define NPT 32                    // points per thread = NPTS/(NPART*TPB)
#define PART_PTS (NPTS / NPART)   // 16384

// One batch = 8 blocks x 512 threads (proven cooperative grid: 256 blocks =
// 1 block/CU). Each thread owns 32 points as named scalars, PINNED into
// VGPRs via an opaque asm copy after load: R8 showed (VGPR_Count=88 with
// 128 live floats) that the compiler otherwise rematerializes the coord
// loads inside the k-loop, re-streaming ~96B/thread/step through L1/L2.
// The asm output is opaque SSA -> not rematerializable -> must stay live
// in registers (~200 VGPR, still 8 waves/CU = 1 block/CU co-resident).
//
// Per step (R6/R8's proven structure):
//   straight-line scan over 32 register-resident points:
//     d2 = fma(dz,dz, fma(dx,dx, dy*dy))   (R4-validated contraction)
//     sd = fminf(sd, sqrtf(d2))            (literally the ref recurrence;
//                                           sqrtf CR per R1==R2 evidence)
//   wave shfl argmax -> LDS -> wave0 cross-wave max -> tagged publish to
//   slot row (agent store) -> wave0 spins on 64B row until all 8 tags match
//   -> wave0 max -> LDS broadcast -> barrier. No atomics, no ws zeroing
//   (tags 1..2047 disambiguate 0xAA poison (tag 0x5555); stale entries from
//   prior replays are bitwise-identical by determinism, so benign).
//
// argmax ties: first-index at every level (strict > ascending n in-thread;
// packed (fbits<<32)|(131071-n) u64-max across lanes/waves/blocks).

#define RPT32(X) X(0)X(1)X(2)X(3)X(4)X(5)X(6)X(7)X(8)X(9)X(10)X(11)X(12) \
  X(13)X(14)X(15)X(16)X(17)X(18)X(19)X(20)X(21)X(22)X(23)X(24)X(25)X(26) \
  X(27)X(28)X(29)X(30)X(31)

__global__ __launch_bounds__(TPB, 1) void fps_kernel(
    const float* __restrict__ x, const int* __restrict__ start,
    int* __restrict__ out, unsigned long long* __restrict__ slot)
{
  #pragma clang fp contract(off)
  const int blk  = blockIdx.x;
  // XCD-clustered: all 8 parts of a batch share blk&7 (same XCD under
  // round-robin dispatch) -> sync row + x slice get L2 locality.
  const int xcd  = blk & 7;
  const int j    = blk >> 3;          // 0..31
  const int b    = xcd * 4 + (j & 3); // 0..31
  const int part = j >> 2;            // 0..7
  const int tid  = threadIdx.x;
  const int lane = tid & 63;
  const int wave = tid >> 6;

  const float* xb = x + (size_t)b * (NPTS * 3);

  // start_idx dtype hedge: int64 (LE, <2^31) => zeros at odd int32 slots.
  bool is64 = true;
  #pragma unroll 1
  for (int i = 1; i < 32; i += 2) {
    if (start[i] != 0) { is64 = false; break; }
  }
  int cur = is64 ? start[2 * b] : start[b];

  const int base = part * PART_PTS + tid;

  // 128 named scalars: px0..pz31 coords, sd0..sd31 running min-dist
  // (sqrt domain -- bitwise the reference's min_d by induction).
  #define DECLP(J) float px##J, py##J, pz##J, sd##J;
  RPT32(DECLP)
  #define INITP(J) { const int n = base + (J) * TPB;          \
      px##J = xb[3*n]; py##J = xb[3*n+1]; pz##J = xb[3*n+2];  \
      sd##J = __builtin_inff(); }
  RPT32(INITP)
  // Pin coords into VGPRs: opaque copy kills load-rematerialization.
  #define PINP(J) asm("" : "+v"(px##J), "+v"(py##J), "+v"(pz##J));
  RPT32(PINP)

  __shared__ unsigned long long wred[TPB / 64];
  __shared__ int snext;

  if (part == 0 && tid == 0) out[b * KSAMP] = cur;  // scan emits idx BEFORE update

  float cx = xb[3 * (size_t)cur + 0];
  float cy = xb[3 * (size_t)cur + 1];
  float cz = xb[3 * (size_t)cur + 2];

  unsigned long long* const srow0 = slot + (size_t)b * 2 * NPART;  // [b][2][8]

  for (int k = 0; k < KSAMP - 1; ++k) {
    float bestv = -1.0f;
    int   bestn = 0;
    #define SCANP(J) {                                              \
      const float dx = px##J - cx;                                  \
      const float dy = py##J - cy;                                  \
      const float dz = pz##J - cz;                                  \
      const float d2 = fmaf(dz, dz, fmaf(dx, dx, dy * dy));         \
      const float m  = fminf(sd##J, sqrtf(d2));                     \
      sd##J = m;                                                    \
      if (m > bestv) { bestv = m; bestn = base + (J) * TPB; }       \
    }
    RPT32(SCANP)

    // pack: higher dist wins; equal dist -> smaller index wins (131071-n).
    // index field bits 0..16; bits 17..31 stay 0 for the step tag.
    unsigned long long key =
        ((unsigned long long)__float_as_uint(bestv) << 32) |
        (unsigned int)(NPTS - 1 - bestn);

    #pragma unroll
    for (int off = 32; off >= 1; off >>= 1) {
      unsigned long long o = __shfl_xor(key, off, 64);
      if (o > key) key = o;
    }
    if (lane == 0) wred[wave] = key;
    __syncthreads();

    if (wave == 0) {
      // cross-wave max: lanes hold wred[lane&7]; 3 xor steps reduce each
      // aligned 8-group (all groups identical) -> block max on all lanes.
      unsigned long long v = wred[lane & 7];
      #pragma unroll
      for (int off = 4; off >= 1; off >>= 1) {
        unsigned long long o = __shfl_xor(v, off, 64);
        if (o > v) v = o;
      }

      const unsigned tag = (unsigned)(k + 1);     // 1..2047, never 0x5555 poison
      unsigned long long* const row = srow0 + (unsigned)(k & 1) * NPART;
      if (lane == 0)
        __hip_atomic_store(&row[part], v | ((unsigned long long)tag << 17),
                           __ATOMIC_RELAXED, __HIP_MEMORY_SCOPE_AGENT);

      // parallel spin on the 64B row until all 8 tags match this step.
      unsigned long long g;
      do {
        g = __hip_atomic_load(&row[lane & (NPART - 1)], __ATOMIC_RELAXED,
                              __HIP_MEMORY_SCOPE_AGENT);
      } while (__ballot(((unsigned)(g >> 17) & 0x7FFFu) == tag) != ~0ull);

      // max over 8 slots (each aligned 8-group identical): 3 xor steps.
      #pragma unroll
      for (int off = 4; off >= 1; off >>= 1) {
        unsigned long long o = __shfl_xor(g, off, 64);
        if (o > g) g = o;
      }
      const int nidx = NPTS - 1 - (int)(g & 0x1FFFFu);
      if (lane == 0) {
        snext = nidx;
        if (part == 0) out[b * KSAMP + k + 1] = nidx;
      }
    }
    __syncthreads();

    const int nidx = snext;
    cx = xb[3 * (size_t)nidx + 0];
    cy = xb[3 * (size_t)nidx + 1];
    cz = xb[3 * (size_t)nidx + 2];
  }
}

extern "C" void kernel_launch(void* const* d_in, const int* in_sizes, int n_in,
                              void* d_out, int out_size, void* d_ws, size_t ws_size,
                              hipStream_t stream) {
  const float* x     = (const float*)d_in[0];
  const int*   start = (const int*)d_in[1];
  int*         out   = (int*)d_out;
  unsigned long long* slot = (unsigned long long*)d_ws;  // [32][2][8] u64 = 4KB

  // No memset needed: step tags (1..2047 in bits 17..31) disambiguate the
  // 0xAA poison (tag 0x5555) and stale values from prior replays (which are
  // bitwise-identical across deterministic replays anyway).
  void* args[] = {(void*)&x, (void*)&start, (void*)&out, (void*)&slot};
  hipLaunchCooperativeKernel((void*)fps_kernel, dim3(NB * NPART), dim3(TPB),
                             args, 0, stream);
}

// Round 10
// 4648.949 us; speedup vs baseline: 1.7356x; 1.7356x over previous
//
#include <hip/hip_runtime.h>

#define NB 32
#define NPTS 131072
#define KSAMP 2048
#define NPART 8
#define TPB 512
#define NPT 32                    // points per thread = NPTS/(NPART*TPB)
#define PART_PTS (NPTS / NPART)   // 16384

// One batch = 8 blocks x 512 threads (proven cooperative grid: 256 blocks =
// 1 block/CU). Each thread owns 32 points as named scalars.
//
// R6-R9 finding: at VGPR_Count=88 the allocator keeps only sd[] resident and
// re-streams 196KB/block of coords from L2/L3 every step (50MB/step chip-
// wide) -- the scan was cache-bound, not VALU-bound, which is why all three
// scan rewrites were time-identical. Fix: amdgpu_waves_per_eu(2,2) pins the
// backend's occupancy target to exactly 2 waves/SIMD (what we run anyway),
// raising the per-wave VGPR budget to 512/2=256 so all 128 per-thread floats
// (96 coords + 32 md2) fit in registers. asm pins kept to forbid remat.
//
// Scan is in d^2 domain (no per-point sqrt):
//   d2  = fma(dz,dz, fma(dx,dx, dy*dy))     (R4-validated contraction)
//   md2 = fminf(md2, d2)
// CR-sqrt monotonicity: RN(sqrt(min md2)) == ref's iterated min(min_d,
// sqrt(d2)) bitwise. Per-thread argmax over md2 (strict >, ascending J =
// first-index), then ONE CR sqrt converts the thread winner to the ref's
// sd domain; the cross-lane/cross-block tree compares (sd_bits<<32)|~idx --
// identical value+first-index semantics to jnp.argmax over min_d. Residual
// risk: intra-thread sqrt-collapse tie at the thread max (~1e-9/step).
//
// Sync per step (R6 proven): wave shfl max -> LDS -> wave0 cross-wave max ->
// tagged publish (agent store) -> wave0 spins on 64B row until all 8 tags
// match -> LDS broadcast -> barrier. No atomics, no ws zeroing (tags 1..2047
// disambiguate 0xAA poison (tag 0x5555) / stale replay data, which is
// bitwise-identical by determinism anyway).

#define RPT32(X) X(0)X(1)X(2)X(3)X(4)X(5)X(6)X(7)X(8)X(9)X(10)X(11)X(12) \
  X(13)X(14)X(15)X(16)X(17)X(18)X(19)X(20)X(21)X(22)X(23)X(24)X(25)X(26) \
  X(27)X(28)X(29)X(30)X(31)

__global__ __launch_bounds__(TPB)
__attribute__((amdgpu_waves_per_eu(2, 2)))
void fps_kernel(
    const float* __restrict__ x, const int* __restrict__ start,
    int* __restrict__ out, unsigned long long* __restrict__ slot)
{
  #pragma clang fp contract(off)
  const int blk  = blockIdx.x;
  // XCD-clustered: all 8 parts of a batch share blk&7 (same XCD under
  // round-robin dispatch) -> sync row + x slice get L2 locality.
  const int xcd  = blk & 7;
  const int j    = blk >> 3;          // 0..31
  const int b    = xcd * 4 + (j & 3); // 0..31
  const int part = j >> 2;            // 0..7
  const int tid  = threadIdx.x;
  const int lane = tid & 63;
  const int wave = tid >> 6;

  const float* xb = x + (size_t)b * (NPTS * 3);

  // start_idx dtype hedge: int64 (LE, <2^31) => zeros at odd int32 slots.
  bool is64 = true;
  #pragma unroll 1
  for (int i = 1; i < 32; i += 2) {
    if (start[i] != 0) { is64 = false; break; }
  }
  int cur = is64 ? start[2 * b] : start[b];

  const int base = part * PART_PTS + tid;

  // 128 named scalars: px/py/pz coords + md2 running min-dist^2.
  #define DECLP(J) float px##J, py##J, pz##J, md2##J;
  RPT32(DECLP)
  #define INITP(J) { const int n = base + (J) * TPB;          \
      px##J = xb[3*n]; py##J = xb[3*n+1]; pz##J = xb[3*n+2];  \
      md2##J = __builtin_inff(); }
  RPT32(INITP)
  // Pin coords into VGPRs: opaque copy forbids load-rematerialization.
  #define PINP(J) asm("" : "+v"(px##J), "+v"(py##J), "+v"(pz##J));
  RPT32(PINP)

  __shared__ unsigned long long wred[TPB / 64];
  __shared__ int snext;

  if (part == 0 && tid == 0) out[b * KSAMP] = cur;  // scan emits idx BEFORE update

  float cx = xb[3 * (size_t)cur + 0];
  float cy = xb[3 * (size_t)cur + 1];
  float cz = xb[3 * (size_t)cur + 2];

  unsigned long long* const srow0 = slot + (size_t)b * 2 * NPART;  // [b][2][8]

  for (int k = 0; k < KSAMP - 1; ++k) {
    float bestv = -1.0f;   // d^2 domain
    int   bestn = 0;
    #define SCANP(J) {                                              \
      const float dx = px##J - cx;                                  \
      const float dy = py##J - cy;                                  \
      const float dz = pz##J - cz;                                  \
      const float d2 = fmaf(dz, dz, fmaf(dx, dx, dy * dy));         \
      const float m  = fminf(md2##J, d2);                           \
      md2##J = m;                                                   \
      if (m > bestv) { bestv = m; bestn = base + (J) * TPB; }       \
    }
    RPT32(SCANP)

    // ONE CR sqrt per thread: convert winner to the reference's sd domain.
    const float sdw = sqrtf(bestv);

    // pack: higher sd wins; equal sd -> smaller index wins (131071-n).
    // index field bits 0..16; bits 17..31 stay 0 for the step tag.
    unsigned long long key =
        ((unsigned long long)__float_as_uint(sdw) << 32) |
        (unsigned int)(NPTS - 1 - bestn);

    #pragma unroll
    for (int off = 32; off >= 1; off >>= 1) {
      unsigned long long o = __shfl_xor(key, off, 64);
      if (o > key) key = o;
    }
    if (lane == 0) wred[wave] = key;
    __syncthreads();

    if (wave == 0) {
      // cross-wave max: lanes hold wred[lane&7]; 3 xor steps reduce each
      // aligned 8-group (all groups identical) -> block max on all lanes.
      unsigned long long v = wred[lane & 7];
      #pragma unroll
      for (int off = 4; off >= 1; off >>= 1) {
        unsigned long long o = __shfl_xor(v, off, 64);
        if (o > v) v = o;
      }

      const unsigned tag = (unsigned)(k + 1);     // 1..2047, never 0x5555 poison
      unsigned long long* const row = srow0 + (unsigned)(k & 1) * NPART;
      if (lane == 0)
        __hip_atomic_store(&row[part], v | ((unsigned long long)tag << 17),
                           __ATOMIC_RELAXED, __HIP_MEMORY_SCOPE_AGENT);

      // parallel spin on the 64B row until all 8 tags match this step.
      unsigned long long g;
      do {
        g = __hip_atomic_load(&row[lane & (NPART - 1)], __ATOMIC_RELAXED,
                              __HIP_MEMORY_SCOPE_AGENT);
      } while (__ballot(((unsigned)(g >> 17) & 0x7FFFu) == tag) != ~0ull);

      // max over 8 slots (each aligned 8-group identical): 3 xor steps.
      #pragma unroll
      for (int off = 4; off >= 1; off >>= 1) {
        unsigned long long o = __shfl_xor(g, off, 64);
        if (o > g) g = o;
      }
      const int nidx = NPTS - 1 - (int)(g & 0x1FFFFu);
      if (lane == 0) {
        snext = nidx;
        if (part == 0) out[b * KSAMP + k + 1] = nidx;
      }
    }
    __syncthreads();

    const int nidx = snext;
    cx = xb[3 * (size_t)nidx + 0];
    cy = xb[3 * (size_t)nidx + 1];
    cz = xb[3 * (size_t)nidx + 2];
  }
}

extern "C" void kernel_launch(void* const* d_in, const int* in_sizes, int n_in,
                              void* d_out, int out_size, void* d_ws, size_t ws_size,
                              hipStream_t stream) {
  const float* x     = (const float*)d_in[0];
  const int*   start = (const int*)d_in[1];
  int*         out   = (int*)d_out;
  unsigned long long* slot = (unsigned long long*)d_ws;  // [32][2][8] u64 = 4KB

  // No memset needed: step tags (1..2047 in bits 17..31) disambiguate the
  // 0xAA poison (tag 0x5555) and stale values from prior replays (which are
  // bitwise-identical across deterministic replays anyway).
  void* args[] = {(void*)&x, (void*)&start, (void*)&out, (void*)&slot};
  hipLaunchCooperativeKernel((void*)fps_kernel, dim3(NB * NPART), dim3(TPB),
                             args, 0, stream);
}